// Round 1
// baseline (239.933 us; speedup 1.0000x reference)
//
#include <hip/hip_runtime.h>

// NeighborList: N=4096 atoms, cutoff 5.0, all unordered pairs i<j.
// Output layout (floats, concatenated):
//   [0,P)        pair_i   (index as float, -1.0 if masked)
//   [P,2P)       pair_j
//   [2P,5P)      pair_diff ([P,3] row-major, 0 if masked)
//   [5P,6P)      pair_dist (0 if masked)
//   [6P]         n_pairs (count as float)
// Strategy: ~0.24% of pairs valid -> bulk float4 fill of constants (write-BW
// bound, 201 MB) + sparse scatter of valid entries (~20k pairs, ~0.5 MB).

__global__ void fill_kernel(float* __restrict__ out, int* __restrict__ ws_count,
                            int total4, int neg4, long long total_elems) {
    int idx = blockIdx.x * blockDim.x + threadIdx.x;
    int stride = gridDim.x * blockDim.x;
    if (idx == 0) *ws_count = 0;
    float4* o = (float4*)out;
    const float4 neg = make_float4(-1.f, -1.f, -1.f, -1.f);
    const float4 zer = make_float4(0.f, 0.f, 0.f, 0.f);
    for (int k = idx; k < total4; k += stride) {
        o[k] = (k < neg4) ? neg : zer;
    }
    // scalar tail (empty for N=4096 since 6P % 4 == 0, kept for safety)
    long long tail_start = (long long)total4 * 4;
    for (long long e = tail_start + idx; e < total_elems; e += stride) {
        out[e] = 0.f;
    }
}

__global__ void pair_kernel(const float* __restrict__ xyz, float* __restrict__ out,
                            int* __restrict__ ws_count, int N, int P) {
    const int i = blockIdx.y;
    // whole-block early exit if every j in this block is <= i
    if (blockIdx.x * blockDim.x + (blockDim.x - 1) <= i) return;
    const int j = blockIdx.x * blockDim.x + threadIdx.x;

    bool valid = false;
    float dx = 0.f, dy = 0.f, dz = 0.f, dist = 0.f;
    int p = 0;
    if (j > i && j < N) {
        // i is block-uniform -> these should become scalar loads
        const float xi = xyz[3 * i + 0];
        const float yi = xyz[3 * i + 1];
        const float zi = xyz[3 * i + 2];
        const float xj = xyz[3 * j + 0];
        const float yj = xyz[3 * j + 1];
        const float zj = xyz[3 * j + 2];
        dx = xi - xj;
        dy = yi - yj;
        dz = zi - zj;
        const float d2 = dx * dx + dy * dy + dz * dz;
        dist = sqrtf(d2);
        valid = dist < 5.0f;  // mirror reference: sqrt then compare
        p = i * (N - 1) - (i * (i - 1)) / 2 + (j - i - 1);
    }

    if (valid) {
        out[p]                 = (float)i;
        out[P + p]             = (float)j;
        out[2 * P + 3 * p + 0] = dx;
        out[2 * P + 3 * p + 1] = dy;
        out[2 * P + 3 * p + 2] = dz;
        out[5 * P + p]         = dist;
    }

    unsigned long long b = __ballot(valid);
    int cnt = __popcll(b);
    if ((threadIdx.x & 63) == 0 && cnt) atomicAdd(ws_count, cnt);
}

__global__ void finalize_kernel(float* __restrict__ out, const int* __restrict__ ws_count,
                                int pos) {
    out[pos] = (float)(*ws_count);
}

extern "C" void kernel_launch(void* const* d_in, const int* in_sizes, int n_in,
                              void* d_out, int out_size, void* d_ws, size_t ws_size,
                              hipStream_t stream) {
    const float* xyz = (const float*)d_in[0];
    float* out = (float*)d_out;
    int* ws_count = (int*)d_ws;

    const int N = in_sizes[0] / 3;                 // 4096
    const long long P = (long long)N * (N - 1) / 2;  // 8,386,560
    const int Pi = (int)P;
    const int total4 = (int)((6 * P) / 4);
    const int neg4 = (int)((2 * P) / 4);

    fill_kernel<<<2048, 256, 0, stream>>>(out, ws_count, total4, neg4, 6 * P);

    dim3 grid((N + 255) / 256, N - 1);  // i in [0, N-2]
    pair_kernel<<<grid, 256, 0, stream>>>(xyz, out, ws_count, N, Pi);

    finalize_kernel<<<1, 1, 0, stream>>>(out, ws_count, (int)(6 * P));
}

// Round 2
// 50.219 us; speedup vs baseline: 4.7777x; 4.7777x over previous
//
#include <hip/hip_runtime.h>

// NeighborList: N=4096 atoms, cutoff 5.0, all unordered pairs i<j (P = N(N-1)/2).
// Output (floats, concat): [0,P) pair_i | [P,2P) pair_j | [2P,5P) diff[P,3]
//                          | [5P,6P) dist | [6P] n_pairs
// Single fused pass: each thread owns one pair p and writes its 6 output
// elements exactly once (valid values or -1/0 constants). Write-BW bound:
// 201 MB -> ~32 us floor. Counting: per-wave ballot -> per-block LDS reduce ->
// one atomic per non-empty block into 1024 hashed slots (kills the R0
// same-address atomic serialization that cost ~200 us).

#define NSLOTS 1024

__global__ void zero_ws(int* __restrict__ ws) {
    int t = blockIdx.x * blockDim.x + threadIdx.x;
    if (t < NSLOTS) ws[t] = 0;
}

__global__ __launch_bounds__(256) void nl_kernel(const float* __restrict__ xyz,
                                                 float* __restrict__ out,
                                                 int* __restrict__ ws,
                                                 int N, int P) {
    const int i = blockIdx.y;              // row, 0..N-2
    const int jb = blockIdx.x * 256;
    if (jb + 255 <= i) return;             // entire block at/below diagonal
    const int j = jb + threadIdx.x;        // always < N (16*256 == N)

    __shared__ int wcnt[4];

    bool valid = false;
    if (j > i) {
        // i is block-uniform -> scalar loads
        const float xi = xyz[3 * i + 0];
        const float yi = xyz[3 * i + 1];
        const float zi = xyz[3 * i + 2];
        const float xj = xyz[3 * j + 0];
        const float yj = xyz[3 * j + 1];
        const float zj = xyz[3 * j + 2];
        const float dx = xi - xj;
        const float dy = yi - yj;
        const float dz = zi - zj;
        const float d2 = dx * dx + dy * dy + dz * dz;
        const float dist = sqrtf(d2);
        valid = dist < 5.0f;               // mirror reference: sqrt then compare

        const int p = i * (N - 1) - (i * (i - 1)) / 2 + (j - i - 1);
        out[p]     = valid ? (float)i : -1.f;
        out[P + p] = valid ? (float)j : -1.f;
        const int q = 2 * P + 3 * p;
        out[q + 0] = valid ? dx : 0.f;
        out[q + 1] = valid ? dy : 0.f;
        out[q + 2] = valid ? dz : 0.f;
        out[5 * P + p] = valid ? dist : 0.f;
    }

    unsigned long long b = __ballot(valid);
    if ((threadIdx.x & 63) == 0) wcnt[threadIdx.x >> 6] = __popcll(b);
    __syncthreads();
    if (threadIdx.x == 0) {
        int c = wcnt[0] + wcnt[1] + wcnt[2] + wcnt[3];
        if (c) atomicAdd(&ws[(blockIdx.y * gridDim.x + blockIdx.x) & (NSLOTS - 1)], c);
    }
}

__global__ void finalize_kernel(float* __restrict__ out, const int* __restrict__ ws,
                                int pos) {
    const int t = threadIdx.x;  // 256 threads
    int s = ws[t] + ws[t + 256] + ws[t + 512] + ws[t + 768];
    for (int o = 32; o > 0; o >>= 1) s += __shfl_down(s, o, 64);
    __shared__ int sh[4];
    if ((t & 63) == 0) sh[t >> 6] = s;
    __syncthreads();
    if (t == 0) out[pos] = (float)(sh[0] + sh[1] + sh[2] + sh[3]);
}

extern "C" void kernel_launch(void* const* d_in, const int* in_sizes, int n_in,
                              void* d_out, int out_size, void* d_ws, size_t ws_size,
                              hipStream_t stream) {
    const float* xyz = (const float*)d_in[0];
    float* out = (float*)d_out;
    int* ws = (int*)d_ws;

    const int N = in_sizes[0] / 3;                    // 4096
    const long long Pll = (long long)N * (N - 1) / 2; // 8,386,560
    const int P = (int)Pll;

    zero_ws<<<4, 256, 0, stream>>>(ws);

    dim3 grid((N + 255) / 256, N - 1);
    nl_kernel<<<grid, 256, 0, stream>>>(xyz, out, ws, N, P);

    finalize_kernel<<<1, 256, 0, stream>>>(out, ws, 6 * P);
}

// Round 3
// 45.419 us; speedup vs baseline: 5.2827x; 1.1057x over previous
//
#include <hip/hip_runtime.h>

// NeighborList: N=4096, cutoff 5.0, all pairs i<j (P = N(N-1)/2 = 8,386,560).
// Output (floats): [0,P) pair_i | [P,2P) pair_j | [2P,5P) diff[P,3] | [5P,6P) dist | [6P] n_pairs
//
// R2: linear-p mapping. Thread t owns pairs p0=4t..4t+3 (consecutive in ALL
// output regions -> aligned float4 stores, zero dead threads). (i,j) recovered
// from p via fp64 inverse-triangular + int fixup. Count: per-block plain store
// to ws[bid] (no atomics), tiny finalize sums. Write-BW bound: 201 MB.

typedef float f4 __attribute__((ext_vector_type(4)));

__global__ void zero_ws(int* __restrict__ ws, int n) {
    int t = blockIdx.x * blockDim.x + threadIdx.x;
    if (t < n) ws[t] = 0;
}

__global__ __launch_bounds__(256) void nl_kernel(const float* __restrict__ xyz,
                                                 float* __restrict__ out,
                                                 int* __restrict__ ws,
                                                 int N, int P, int slots) {
    const int p0 = (blockIdx.x * 256 + threadIdx.x) * 4;
    int cnt = 0;
    if (p0 < P) {
        // invert p -> row i: rowstart(i) = i*(2N-1-i)/2 <= p
        const double twoNm1 = (double)(2 * N - 1);
        int i = (int)((twoNm1 - sqrt(twoNm1 * twoNm1 - 8.0 * (double)p0)) * 0.5);
        if (i > N - 2) i = N - 2;
        if (i < 0) i = 0;
        int rs = i * (2 * N - 1 - i) / 2;
        while (p0 < rs) { --i; rs -= (N - 1 - i); }          // safety fixup
        int next = rs + (N - 1 - i);
        while (p0 >= next && i < N - 2) { ++i; rs = next; next += (N - 1 - i); }

        float iv[4], jv[4], dxs[4], dys[4], dzs[4], dv[4];
        #pragma unroll
        for (int e = 0; e < 4; ++e) {
            const int p = p0 + e;
            while (p >= next && i < N - 2) { ++i; rs = next; next += (N - 1 - i); }
            const int j = i + 1 + (p - rs);
            float dx = 0.f, dy = 0.f, dz = 0.f, dist = 0.f, fi = -1.f, fj = -1.f;
            if (p < P) {
                const float ax = xyz[3 * i], ay = xyz[3 * i + 1], az = xyz[3 * i + 2];
                const float bx = xyz[3 * j], by = xyz[3 * j + 1], bz = xyz[3 * j + 2];
                const float tx = ax - bx, ty = ay - by, tz = az - bz;
                const float d = sqrtf(tx * tx + ty * ty + tz * tz);
                if (d < 5.0f) {                    // mirror reference: sqrt then compare
                    fi = (float)i; fj = (float)j;
                    dx = tx; dy = ty; dz = tz; dist = d;
                    ++cnt;
                }
            }
            iv[e] = fi; jv[e] = fj; dxs[e] = dx; dys[e] = dy; dzs[e] = dz; dv[e] = dist;
        }

        if (p0 + 4 <= P) {   // p0 mult of 4 -> all these are 16B-aligned
            *(f4*)(out + p0)     = (f4){iv[0], iv[1], iv[2], iv[3]};
            *(f4*)(out + P + p0) = (f4){jv[0], jv[1], jv[2], jv[3]};
            f4* dp = (f4*)(out + 2 * P + 3 * p0);
            dp[0] = (f4){dxs[0], dys[0], dzs[0], dxs[1]};
            dp[1] = (f4){dys[1], dzs[1], dxs[2], dys[2]};
            dp[2] = (f4){dzs[2], dxs[3], dys[3], dzs[3]};
            *(f4*)(out + 5 * P + p0) = (f4){dv[0], dv[1], dv[2], dv[3]};
        } else {
            for (int e = 0; e < 4 && p0 + e < P; ++e) {
                const int p = p0 + e;
                out[p] = iv[e]; out[P + p] = jv[e];
                out[2 * P + 3 * p]     = dxs[e];
                out[2 * P + 3 * p + 1] = dys[e];
                out[2 * P + 3 * p + 2] = dzs[e];
                out[5 * P + p] = dv[e];
            }
        }
    }

    // per-block count -> ws (plain store if ws has a slot per block, else hashed atomic)
    for (int o = 32; o > 0; o >>= 1) cnt += __shfl_down(cnt, o, 64);
    __shared__ int sh[4];
    if ((threadIdx.x & 63) == 0) sh[threadIdx.x >> 6] = cnt;
    __syncthreads();
    if (threadIdx.x == 0) {
        const int c = sh[0] + sh[1] + sh[2] + sh[3];
        if ((int)gridDim.x <= slots) ws[blockIdx.x] = c;
        else if (c) atomicAdd(&ws[blockIdx.x % slots], c);
    }
}

__global__ void finalize_kernel(float* __restrict__ out, const int* __restrict__ ws,
                                int n, int pos) {
    const int t = threadIdx.x;  // 256
    int s = 0;
    for (int k = t; k < n; k += 256) s += ws[k];
    for (int o = 32; o > 0; o >>= 1) s += __shfl_down(s, o, 64);
    __shared__ int sh[4];
    if ((t & 63) == 0) sh[t >> 6] = s;
    __syncthreads();
    if (t == 0) out[pos] = (float)(sh[0] + sh[1] + sh[2] + sh[3]);
}

extern "C" void kernel_launch(void* const* d_in, const int* in_sizes, int n_in,
                              void* d_out, int out_size, void* d_ws, size_t ws_size,
                              hipStream_t stream) {
    const float* xyz = (const float*)d_in[0];
    float* out = (float*)d_out;
    int* ws = (int*)d_ws;

    const int N = in_sizes[0] / 3;                          // 4096
    const int P = (int)((long long)N * (N - 1) / 2);        // 8,386,560

    const int nb = (P + 1023) / 1024;                       // 4 pairs/thread, 256 thr/block
    const int cap = (int)(ws_size / 4);
    const int slots = (nb <= cap) ? nb : (cap < 1 ? 1 : (cap > 1024 ? 1024 : cap));
    if (nb > slots) zero_ws<<<(slots + 255) / 256, 256, 0, stream>>>(ws, slots);

    nl_kernel<<<nb, 256, 0, stream>>>(xyz, out, ws, N, P, slots);
    finalize_kernel<<<1, 256, 0, stream>>>(out, ws, slots, 6 * P);
}